// Round 4
// baseline (1358.356 us; speedup 1.0000x reference)
//
#include <hip/hip_runtime.h>
#include <hip/hip_fp16.h>
#include <hip/hip_cooperative_groups.h>

namespace cg = cooperative_groups;

// ---------------------------------------------------------------------------
// GCN: 4 layers of  h' = A_hat_norm (h @ W) + b   on fixed graph, fp32.
// deg[i] = in_degree(i) + 1 (self loop), dinv = 1/sqrt(deg),
// g = (h@W) * dinv[row]  (GEMM epilogue), then per-dst:
//   h'[dst] = dinv[dst] * ( g[dst] + sum_{src in N(dst)} g[src] ) + b
// R3: CSR fill via binned counting sort. R4: LDS per-bin CSR build. (784us)
// R9/R10: gather MLP 8->16 rows in flight. (748us) fp32 agg miss-path-bound.
// R11: fp16 G. FETCH 161MB, agg 71us, total 587us.
// R12: 32 rows in flight, byte-offset col, scalarized rowptr. (579us, agg
//   69.8us). MLP x2 again = null -> agg pinned at L2 random-fill rate:
//   1.26M fills/70us = EXACTLY 1.0 fill/cyc/XCD. Structural ~70us floor
//   (8x cold replication of G across per-XCD L2s, only 1.4x headroom).
// R13: kernel-sum (~350us) vs wall (579us) leaves ~200us of dispatch
//   overhead across 14 launches. Fuse the 8 layer kernels into ONE
//   cooperative kernel with grid.sync() between phases; W amortized in
//   LDS per phase; agg/gemm bodies unchanged (no numeric delta).
//   Dispatches 14 -> 6. Predict: wall 579 -> ~420-470 if gap = overhead;
//   ~580 if not (that outcome = diagnosis, pivot to Y-fp16+CSR next).
// ---------------------------------------------------------------------------

#define FEAT 128
#define EMB 64
#define BINSHIFT 8
#define BINSIZE 256
#define NBIN 391          // ceil(100000/256)
#define CHUNK 8192

// ---------------- CSR build (unchanged, proven) ----------------

__global__ __launch_bounds__(256) void bin_count_k(
    const int* __restrict__ dst, int* __restrict__ bincnt, int E) {
    __shared__ int hist[NBIN];
    int t = threadIdx.x;
    int base = blockIdx.x * CHUNK;
    int end = min(base + CHUNK, E);
    for (int i = t; i < NBIN; i += 256) hist[i] = 0;
    __syncthreads();
    for (int e = base + t; e < end; e += 256)
        atomicAdd(&hist[dst[e] >> BINSHIFT], 1);
    __syncthreads();
    for (int b = t; b < NBIN; b += 256) {
        int c = hist[b];
        if (c > 0) atomicAdd(&bincnt[b], c);
    }
}

__global__ void binscan_k(const int* __restrict__ bincnt, int* __restrict__ binptr,
                          int* __restrict__ bincur, int nbin, int E) {
    __shared__ int s[512];
    int t = threadIdx.x;
    int v = (t < nbin) ? bincnt[t] : 0;
    s[t] = v;
    __syncthreads();
    for (int off = 1; off < 512; off <<= 1) {
        int tv = (t >= off) ? s[t - off] : 0;
        __syncthreads();
        s[t] += tv;
        __syncthreads();
    }
    if (t < nbin) {
        int excl = s[t] - v;
        binptr[t] = excl;
        bincur[t] = excl;
    }
    if (t == 0) binptr[nbin] = E;
}

__global__ __launch_bounds__(256) void bin_edges_k(
    const int* __restrict__ src, const int* __restrict__ dst,
    int* __restrict__ bincur, int* __restrict__ ebuf, int E) {
    __shared__ int hist[NBIN];
    __shared__ int lcur[NBIN];
    int t = threadIdx.x;
    int base = blockIdx.x * CHUNK;
    int end = min(base + CHUNK, E);
    for (int i = t; i < NBIN; i += 256) hist[i] = 0;
    __syncthreads();
    for (int e = base + t; e < end; e += 256)
        atomicAdd(&hist[dst[e] >> BINSHIFT], 1);
    __syncthreads();
    for (int b = t; b < NBIN; b += 256) {
        int c = hist[b];
        lcur[b] = (c > 0) ? atomicAdd(&bincur[b], c) : 0;
    }
    __syncthreads();
    for (int e = base + t; e < end; e += 256) {
        int d = dst[e];
        int bin = d >> BINSHIFT;
        int r = atomicAdd(&lcur[bin], 1);
        ebuf[r] = src[e] | ((d & (BINSIZE - 1)) << 24);
    }
}

__global__ __launch_bounds__(256) void build_csr_k(
    const int* __restrict__ ebuf, const int* __restrict__ binptr,
    int* __restrict__ rowptr, float* __restrict__ dinv,
    int* __restrict__ col, int N, int E, int nbin) {
    __shared__ int lcnt[BINSIZE];
    __shared__ int lscan[BINSIZE];
    __shared__ int lcur[BINSIZE];
    int b = blockIdx.x;
    int t = threadIdx.x;
    int n0 = b << BINSHIFT;
    int e0 = binptr[b];
    int e1 = binptr[b + 1];

    lcnt[t] = 0;
    __syncthreads();
    for (int i = e0 + t; i < e1; i += 256)
        atomicAdd(&lcnt[((unsigned)ebuf[i]) >> 24], 1);
    __syncthreads();

    int v = lcnt[t];
    lscan[t] = v;
    __syncthreads();
    for (int off = 1; off < 256; off <<= 1) {
        int tv = (t >= off) ? lscan[t - off] : 0;
        __syncthreads();
        lscan[t] += tv;
        __syncthreads();
    }
    int excl = e0 + lscan[t] - v;
    lcur[t] = excl;
    if (n0 + t < N) {
        rowptr[n0 + t] = excl;
        dinv[n0 + t] = 1.0f / sqrtf((float)(v + 1));
    }
    if (b == nbin - 1 && t == 0) rowptr[N] = E;
    __syncthreads();

    for (int i = e0 + t; i < e1; i += 256) {
        int w = ebuf[i];
        int dl = ((unsigned)w) >> 24;
        int p = atomicAdd(&lcur[dl], 1);
        col[p] = (w & 0xFFFFFF) << 7;   // byte offset into fp16 G (row = 128B)
    }
}

// ---------------- fused 8-phase layer kernel ----------------

struct FusedArgs {
    const float* x;
    const float* W0; const float* b0;
    const float* W1; const float* b1;
    const float* W2; const float* b2;
    const float* W3; const float* b3;
    const float* Wout; const float* bout;
    const float* dinv;
    const int* rowptr;
    const int* coff;
    __half* G;
    float* Y;
    float* Out;
    int N;
};

// GEMM phase: G = (H @ W) * dinv[row], fp16 out. W staged in LDS once per
// phase (amortized over all grid-stride tiles). 64x64 tile, 4x4 per thread.
template <int K>
__device__ __forceinline__ void gemm_phase(
    const float* __restrict__ H, const float* __restrict__ W,
    const float* __restrict__ dinv, __half* __restrict__ G,
    int N, float* Ws) {
    int t = threadIdx.x;
    for (int i = t * 4; i < K * EMB; i += 1024)
        *(float4*)(Ws + i) = *(const float4*)(W + i);
    __syncthreads();

    int tc = t & 15;   // col group -> 4 cols
    int tr = t >> 4;   // row group -> 4 rows
    int j0 = tc * 4;
    int ntile = (N + 63) >> 6;

    for (int tile = blockIdx.x; tile < ntile; tile += gridDim.x) {
        int r0 = tile * 64 + tr * 4;
        const float* hp[4];
#pragma unroll
        for (int i = 0; i < 4; i++) {
            int r = (r0 + i < N) ? (r0 + i) : (N - 1);
            hp[i] = H + (size_t)r * K;
        }

        float acc[4][4] = {{0.f}};
        float4 a[4], an[4];
#pragma unroll
        for (int i = 0; i < 4; i++) a[i] = *(const float4*)(hp[i]);

#pragma unroll 1
        for (int k = 0; k < K; k += 4) {
            if (k + 4 < K) {
#pragma unroll
                for (int i = 0; i < 4; i++) an[i] = *(const float4*)(hp[i] + k + 4);
            }
#pragma unroll
            for (int kk = 0; kk < 4; kk++) {
                float4 wv = *(const float4*)(Ws + (k + kk) * EMB + j0);
#pragma unroll
                for (int i = 0; i < 4; i++) {
                    float av = (kk == 0) ? a[i].x : (kk == 1) ? a[i].y
                             : (kk == 2) ? a[i].z : a[i].w;
                    acc[i][0] = fmaf(av, wv.x, acc[i][0]);
                    acc[i][1] = fmaf(av, wv.y, acc[i][1]);
                    acc[i][2] = fmaf(av, wv.z, acc[i][2]);
                    acc[i][3] = fmaf(av, wv.w, acc[i][3]);
                }
            }
#pragma unroll
            for (int i = 0; i < 4; i++) a[i] = an[i];
        }

#pragma unroll
        for (int i = 0; i < 4; i++) {
            if (r0 + i < N) {
                float s = dinv[r0 + i];
                union { __half2 h2[2]; float2 f2; } o;
                o.h2[0] = __floats2half2_rn(acc[i][0] * s, acc[i][1] * s);
                o.h2[1] = __floats2half2_rn(acc[i][2] * s, acc[i][3] * s);
                *(float2*)(G + (size_t)(r0 + i) * EMB + j0) = o.f2;
            }
        }
    }
}

// ---- aggregation (R12 body): 8 lanes per 128B fp16 row, 32 rows in flight ----

__device__ __forceinline__ void h8_acc(float (&a)[8], float4 raw) {
    union { float4 f4; __half2 h2[4]; } u;
    u.f4 = raw;
    float2 p0 = __half22float2(u.h2[0]);
    float2 p1 = __half22float2(u.h2[1]);
    float2 p2 = __half22float2(u.h2[2]);
    float2 p3 = __half22float2(u.h2[3]);
    a[0] += p0.x; a[1] += p0.y; a[2] += p1.x; a[3] += p1.y;
    a[4] += p2.x; a[5] += p2.y; a[6] += p3.x; a[7] += p3.y;
}

__device__ __forceinline__ void agg_node8(const __half* __restrict__ G,
                                          const int* __restrict__ coff,
                                          int s, int e, int selfoff,
                                          int grp, int f8, float (&r)[8]) {
    const char* Gb = (const char*)G + f8 * 16;   // lane's 16B slice in a row
    float a0[8] = {0.f, 0.f, 0.f, 0.f, 0.f, 0.f, 0.f, 0.f};
    float a1[8] = {0.f, 0.f, 0.f, 0.f, 0.f, 0.f, 0.f, 0.f};
    float a2[8] = {0.f, 0.f, 0.f, 0.f, 0.f, 0.f, 0.f, 0.f};
    float a3[8] = {0.f, 0.f, 0.f, 0.f, 0.f, 0.f, 0.f, 0.f};
    if (grp == 0) h8_acc(a0, *(const float4*)(Gb + selfoff));  // self loop

    int i = s;
    if (i + 32 <= e) {
        int c0 = coff[i + grp];
        int c1 = coff[i + 8 + grp];
        int c2 = coff[i + 16 + grp];
        int c3 = coff[i + 24 + grp];
        while (true) {
            float4 g0 = *(const float4*)(Gb + (size_t)(unsigned)c0);
            float4 g1 = *(const float4*)(Gb + (size_t)(unsigned)c1);
            float4 g2 = *(const float4*)(Gb + (size_t)(unsigned)c2);
            float4 g3 = *(const float4*)(Gb + (size_t)(unsigned)c3);
            i += 32;
            bool more = (i + 32 <= e);
            if (more) {                       // prefetch next iter's offsets
                c0 = coff[i + grp];
                c1 = coff[i + 8 + grp];
                c2 = coff[i + 16 + grp];
                c3 = coff[i + 24 + grp];
            }
            h8_acc(a0, g0);
            h8_acc(a1, g1);
            h8_acc(a2, g2);
            h8_acc(a3, g3);
            if (!more) break;
        }
    }
    for (; i + 8 <= e; i += 8) {
        float4 g = *(const float4*)(Gb + (size_t)(unsigned)coff[i + grp]);
        h8_acc(a1, g);
    }
    if (grp < e - i) {
        float4 g = *(const float4*)(Gb + (size_t)(unsigned)coff[i + grp]);
        h8_acc(a2, g);
    }

#pragma unroll
    for (int k = 0; k < 8; k++) {
        float v = (a0[k] + a1[k]) + (a2[k] + a3[k]);
        v += __shfl_xor(v, 8, 64);
        v += __shfl_xor(v, 16, 64);
        v += __shfl_xor(v, 32, 64);
        r[k] = v;   // all 64 lanes: full sum for features [8*f8 .. 8*f8+7]
    }
}

__device__ __forceinline__ void agg_phase(
    const __half* __restrict__ G, const float* __restrict__ dinv,
    const int* __restrict__ rowptr, const int* __restrict__ coff,
    const float* __restrict__ bias, float* __restrict__ Hout, int N) {
    int wid = threadIdx.x >> 6;
    int lane = threadIdx.x & 63;
    int grp = lane >> 3;
    int f8 = lane & 7;
    int ngrp = (N + 3) >> 2;
    for (int gq = blockIdx.x; gq < ngrp; gq += gridDim.x) {
        int gw = gq * 4 + wid;
        if (gw >= N) continue;                       // wave-uniform
        gw = __builtin_amdgcn_readfirstlane(gw);     // -> scalar loads
        int s = rowptr[gw], e = rowptr[gw + 1];
        float r[8];
        agg_node8(G, coff, s, e, gw << 7, grp, f8, r);
        if (grp == 0) {
            float d = dinv[gw];
            float4 b0v = *(const float4*)(bias + f8 * 8);
            float4 b1v = *(const float4*)(bias + f8 * 8 + 4);
            float4 lo = make_float4(r[0] * d + b0v.x, r[1] * d + b0v.y,
                                    r[2] * d + b0v.z, r[3] * d + b0v.w);
            float4 hi = make_float4(r[4] * d + b1v.x, r[5] * d + b1v.y,
                                    r[6] * d + b1v.z, r[7] * d + b1v.w);
            float* o = Hout + (size_t)gw * EMB + f8 * 8;
            *(float4*)o = lo;
            *(float4*)(o + 4) = hi;
        }
    }
}

__device__ __forceinline__ void agg_final_phase(
    const __half* __restrict__ G, const float* __restrict__ dinv,
    const int* __restrict__ rowptr, const int* __restrict__ coff,
    const float* __restrict__ bias, const float* __restrict__ Wout,
    const float* __restrict__ bout, float* __restrict__ Y,
    float* __restrict__ Out, int N) {
    int wid = threadIdx.x >> 6;
    int lane = threadIdx.x & 63;
    int grp = lane >> 3;
    int f8 = lane & 7;
    int ngrp = (N + 3) >> 2;
    for (int gq = blockIdx.x; gq < ngrp; gq += gridDim.x) {
        int gw = gq * 4 + wid;
        if (gw >= N) continue;
        gw = __builtin_amdgcn_readfirstlane(gw);
        int s = rowptr[gw], e = rowptr[gw + 1];
        float r[8];
        agg_node8(G, coff, s, e, gw << 7, grp, f8, r);
        float d = dinv[gw];
        float4 b0v = *(const float4*)(bias + f8 * 8);
        float4 b1v = *(const float4*)(bias + f8 * 8 + 4);
        float v0 = r[0] * d + b0v.x, v1 = r[1] * d + b0v.y;
        float v2 = r[2] * d + b0v.z, v3 = r[3] * d + b0v.w;
        float v4 = r[4] * d + b1v.x, v5 = r[5] * d + b1v.y;
        float v6 = r[6] * d + b1v.z, v7 = r[7] * d + b1v.w;
        if (grp == 0) {
            float* o = Y + (size_t)gw * EMB + f8 * 8;
            *(float4*)o = make_float4(v0, v1, v2, v3);
            *(float4*)(o + 4) = make_float4(v4, v5, v6, v7);
        }
        float4 w0v = *(const float4*)(Wout + f8 * 8);
        float4 w1v = *(const float4*)(Wout + f8 * 8 + 4);
        float p = v0 * w0v.x + v1 * w0v.y + v2 * w0v.z + v3 * w0v.w +
                  v4 * w1v.x + v5 * w1v.y + v6 * w1v.z + v7 * w1v.w;
        p += __shfl_xor(p, 1, 8);
        p += __shfl_xor(p, 2, 8);
        p += __shfl_xor(p, 4, 8);
        if (lane == 0) Out[gw] = p + bout[0];
    }
}

__global__ __launch_bounds__(256, 4) void fused_k(FusedArgs A) {
    cg::grid_group grid = cg::this_grid();
    __shared__ float Ws[FEAT * EMB];   // 32KB: max over phases (K=128)

    gemm_phase<FEAT>(A.x, A.W0, A.dinv, A.G, A.N, Ws);
    grid.sync();
    agg_phase(A.G, A.dinv, A.rowptr, A.coff, A.b0, A.Y, A.N);
    grid.sync();
    gemm_phase<EMB>(A.Y, A.W1, A.dinv, A.G, A.N, Ws);
    grid.sync();
    agg_phase(A.G, A.dinv, A.rowptr, A.coff, A.b1, A.Y, A.N);
    grid.sync();
    gemm_phase<EMB>(A.Y, A.W2, A.dinv, A.G, A.N, Ws);
    grid.sync();
    agg_phase(A.G, A.dinv, A.rowptr, A.coff, A.b2, A.Y, A.N);
    grid.sync();
    gemm_phase<EMB>(A.Y, A.W3, A.dinv, A.G, A.N, Ws);
    grid.sync();
    agg_final_phase(A.G, A.dinv, A.rowptr, A.coff, A.b3, A.Wout, A.bout,
                    A.Y, A.Out, A.N);
}

// ---------------- launch ----------------

extern "C" void kernel_launch(void* const* d_in, const int* in_sizes, int n_in,
                              void* d_out, int out_size, void* d_ws, size_t ws_size,
                              hipStream_t stream) {
    const float* x    = (const float*)d_in[0];
    const int*   ei   = (const int*)d_in[1];
    const float* W0   = (const float*)d_in[3];
    const float* b0   = (const float*)d_in[4];
    const float* W1   = (const float*)d_in[5];
    const float* b1   = (const float*)d_in[6];
    const float* W2   = (const float*)d_in[7];
    const float* b2   = (const float*)d_in[8];
    const float* W3   = (const float*)d_in[9];
    const float* b3   = (const float*)d_in[10];
    const float* Wout = (const float*)d_in[11];
    const float* bout = (const float*)d_in[12];

    const int N = in_sizes[0] / FEAT;      // 100000
    const int E = in_sizes[1] / 2;         // 3200000
    const int* srcp = ei;                  // edge_index[0]
    const int* dstp = ei + E;              // edge_index[1]
    const int nbin = (N + BINSIZE - 1) / BINSIZE;   // 391

    // workspace layout (regions padded to 64 elems for float4 alignment)
    const int NP = ((N + 64) + 63) / 64 * 64;   // holds N+1
    float* dinv  = (float*)d_ws;
    int* rowptr  = (int*)(dinv + NP);
    int* bincnt  = rowptr + NP;
    int* binptr  = bincnt + 1024;
    int* bincur  = binptr + 1024;
    int* col     = bincur + 1024;
    float* bufA  = (float*)(col + ((E + 63) / 64) * 64);
    int* ebuf    = (int*)bufA;            // aliased: ebuf dead before first gemm
    __half* Gbuf = (__half*)bufA;         // fp16 G (12.8MB) also aliases here

    float* Out = (float*)d_out;
    float* Y   = Out + N;                 // reuse y-region of d_out as ping-pong buffer

    const int nchunk = (E + CHUNK - 1) / CHUNK;

    // --- CSR build ---
    hipMemsetAsync(bincnt, 0, 1024 * sizeof(int), stream);
    bin_count_k<<<nchunk, 256, 0, stream>>>(dstp, bincnt, E);
    binscan_k<<<1, 512, 0, stream>>>(bincnt, binptr, bincur, nbin, E);
    bin_edges_k<<<nchunk, 256, 0, stream>>>(srcp, dstp, bincur, ebuf, E);
    build_csr_k<<<nbin, 256, 0, stream>>>(ebuf, binptr, rowptr, dinv, col, N, E, nbin);

    // --- fused 4x (gemm -> agg) cooperative kernel ---
    static int nblk = 0;
    if (nblk == 0) {
        int bpc = 0;
        hipError_t err = hipOccupancyMaxActiveBlocksPerMultiprocessor(
            &bpc, (const void*)fused_k, 256, 0);
        if (err != hipSuccess || bpc < 1) bpc = 4;
        if (bpc > 4) bpc = 4;              // conservative: 4 blocks/CU
        nblk = bpc * 256;                  // MI355X: 256 CUs
    }
    FusedArgs fa;
    fa.x = x;
    fa.W0 = W0; fa.b0 = b0;
    fa.W1 = W1; fa.b1 = b1;
    fa.W2 = W2; fa.b2 = b2;
    fa.W3 = W3; fa.b3 = b3;
    fa.Wout = Wout; fa.bout = bout;
    fa.dinv = dinv;
    fa.rowptr = rowptr;
    fa.coff = col;
    fa.G = Gbuf;
    fa.Y = Y;
    fa.Out = Out;
    fa.N = N;
    void* kargs[] = { &fa };
    hipLaunchCooperativeKernel((void*)fused_k, dim3(nblk), dim3(256),
                               kargs, 0, stream);
}

// Round 5
// 555.221 us; speedup vs baseline: 2.4465x; 2.4465x over previous
//
#include <hip/hip_runtime.h>
#include <hip/hip_fp16.h>

// ---------------------------------------------------------------------------
// GCN: 4 layers of  h' = A_hat_norm (h @ W) + b   on fixed graph, fp32.
// deg[i] = in_degree(i) + 1 (self loop), dinv = 1/sqrt(deg),
// g = (h@W) * dinv[row]  (GEMM epilogue), then per-dst:
//   h'[dst] = dinv[dst] * ( g[dst] + sum_{src in N(dst)} g[src] ) + b
// R3: CSR fill via binned counting sort. R4: LDS per-bin CSR build. (784us)
// R9/R10: gather MLP 8->16 rows in flight. (748us) fp32 agg miss-path-bound.
// R11: fp16 G. FETCH 161MB, agg 71us, total 587us.
// R12: 32 rows in flight, byte-offset col, scalarized rowptr. (579us, agg
//   69.8us). Agg pinned at L2 random-fill rate: 1.0 fill/cyc/XCD. ~70us floor.
// R13: cooperative fusion of 8 layer kernels. 1358us — CATASTROPHIC, reverted.
//   grid.sync() (sleep-backoff spin + device fences) ate ~800us. BUT the
//   accounting payoff: wall-minus-fused shows CSR chain + ALL launch gaps
//   ~= 10us. So R12's ledger is: 280 agg + 10 CSR + ~25 gaps + ~265 GEMM.
//   The GEMMs are ~66us each vs ~10us roofline: latency-bound on dependent
//   per-thread global H loads (1-deep prefetch, 300-900cy chain).
// R14: R12 structure + GEMM rewritten with LDS-staged A-tile (BK=64 chunks,
//   padded stride 68 -> 2-way banks = free; Ws broadcast reads). All compute
//   reads from LDS; staging is bulk-coalesced. Same fma order -> bit-identical.
//   Predict: gemm 66 -> 12-18us each, wall 579 -> ~380-420us, agg unchanged.
// ---------------------------------------------------------------------------

#define FEAT 128
#define EMB 64
#define BINSHIFT 8
#define BINSIZE 256
#define NBIN 391          // ceil(100000/256)
#define CHUNK 8192

// ---------------- CSR build (unchanged, proven) ----------------

__global__ __launch_bounds__(256) void bin_count_k(
    const int* __restrict__ dst, int* __restrict__ bincnt, int E) {
    __shared__ int hist[NBIN];
    int t = threadIdx.x;
    int base = blockIdx.x * CHUNK;
    int end = min(base + CHUNK, E);
    for (int i = t; i < NBIN; i += 256) hist[i] = 0;
    __syncthreads();
    for (int e = base + t; e < end; e += 256)
        atomicAdd(&hist[dst[e] >> BINSHIFT], 1);
    __syncthreads();
    for (int b = t; b < NBIN; b += 256) {
        int c = hist[b];
        if (c > 0) atomicAdd(&bincnt[b], c);
    }
}

__global__ void binscan_k(const int* __restrict__ bincnt, int* __restrict__ binptr,
                          int* __restrict__ bincur, int nbin, int E) {
    __shared__ int s[512];
    int t = threadIdx.x;
    int v = (t < nbin) ? bincnt[t] : 0;
    s[t] = v;
    __syncthreads();
    for (int off = 1; off < 512; off <<= 1) {
        int tv = (t >= off) ? s[t - off] : 0;
        __syncthreads();
        s[t] += tv;
        __syncthreads();
    }
    if (t < nbin) {
        int excl = s[t] - v;
        binptr[t] = excl;
        bincur[t] = excl;
    }
    if (t == 0) binptr[nbin] = E;
}

__global__ __launch_bounds__(256) void bin_edges_k(
    const int* __restrict__ src, const int* __restrict__ dst,
    int* __restrict__ bincur, int* __restrict__ ebuf, int E) {
    __shared__ int hist[NBIN];
    __shared__ int lcur[NBIN];
    int t = threadIdx.x;
    int base = blockIdx.x * CHUNK;
    int end = min(base + CHUNK, E);
    for (int i = t; i < NBIN; i += 256) hist[i] = 0;
    __syncthreads();
    for (int e = base + t; e < end; e += 256)
        atomicAdd(&hist[dst[e] >> BINSHIFT], 1);
    __syncthreads();
    for (int b = t; b < NBIN; b += 256) {
        int c = hist[b];
        lcur[b] = (c > 0) ? atomicAdd(&bincur[b], c) : 0;
    }
    __syncthreads();
    for (int e = base + t; e < end; e += 256) {
        int d = dst[e];
        int bin = d >> BINSHIFT;
        int r = atomicAdd(&lcur[bin], 1);
        ebuf[r] = src[e] | ((d & (BINSIZE - 1)) << 24);
    }
}

__global__ __launch_bounds__(256) void build_csr_k(
    const int* __restrict__ ebuf, const int* __restrict__ binptr,
    int* __restrict__ rowptr, float* __restrict__ dinv,
    int* __restrict__ col, int N, int E, int nbin) {
    __shared__ int lcnt[BINSIZE];
    __shared__ int lscan[BINSIZE];
    __shared__ int lcur[BINSIZE];
    int b = blockIdx.x;
    int t = threadIdx.x;
    int n0 = b << BINSHIFT;
    int e0 = binptr[b];
    int e1 = binptr[b + 1];

    lcnt[t] = 0;
    __syncthreads();
    for (int i = e0 + t; i < e1; i += 256)
        atomicAdd(&lcnt[((unsigned)ebuf[i]) >> 24], 1);
    __syncthreads();

    int v = lcnt[t];
    lscan[t] = v;
    __syncthreads();
    for (int off = 1; off < 256; off <<= 1) {
        int tv = (t >= off) ? lscan[t - off] : 0;
        __syncthreads();
        lscan[t] += tv;
        __syncthreads();
    }
    int excl = e0 + lscan[t] - v;
    lcur[t] = excl;
    if (n0 + t < N) {
        rowptr[n0 + t] = excl;
        dinv[n0 + t] = 1.0f / sqrtf((float)(v + 1));
    }
    if (b == nbin - 1 && t == 0) rowptr[N] = E;
    __syncthreads();

    for (int i = e0 + t; i < e1; i += 256) {
        int w = ebuf[i];
        int dl = ((unsigned)w) >> 24;
        int p = atomicAdd(&lcur[dl], 1);
        col[p] = (w & 0xFFFFFF) << 7;   // byte offset into fp16 G (row = 128B)
    }
}

// ---------------- GEMM + dinv row-scale:  G = (H @ W) * dinv[row], fp16 out ----
// R14: A-tile staged in LDS in BK=64 chunks. 64x64 output tile, 4x4/thread.
// As padded to stride 68 floats: 4-row stride = 272 floats -> banks
// alternate +16 -> 2-way (free). Ws reads: 16 lanes broadcast x4 -> 2-way.
// All inner-loop reads are LDS (~120cy) instead of global (300-900cy).
// Same fma order as R12 -> bit-identical output.

#define AKP 68   // padded A-tile row stride in floats (BK=64 + 4)

template <int K>
__global__ __launch_bounds__(256) void gemm_scale_k(
    const float* __restrict__ H, const float* __restrict__ W,
    const float* __restrict__ dinv, __half* __restrict__ G, int N) {
    __shared__ float Ws[K * EMB];        // B: K x 64  (16/32 KB)
    __shared__ float As[64 * AKP];       // A chunk: 64 rows x 64 (+4 pad) = 17 KB
    int t = threadIdx.x;
    int r0blk = blockIdx.x * 64;

    // stage W (coalesced float4)
    for (int i = t * 4; i < K * EMB; i += 1024)
        *(float4*)(Ws + i) = *(const float4*)(W + i);

    int tc = t & 15;   // col group -> 4 cols
    int tr = t >> 4;   // row group -> 4 rows
    int j0 = tc * 4;
    int r0 = r0blk + tr * 4;

    float acc[4][4] = {{0.f}};

    for (int k0 = 0; k0 < K; k0 += 64) {
        // stage A chunk: 64 rows x 64 floats, fully coalesced.
        // 1024 float4 slots; thread t does 4 of them.
#pragma unroll
        for (int n = 0; n < 4; n++) {
            int idx = t + n * 256;
            int row = idx >> 4;          // 16 float4 per row
            int cg  = idx & 15;
            int r = r0blk + row;
            if (r >= N) r = N - 1;       // clamp (harmless dup read)
            *(float4*)(As + row * AKP + cg * 4) =
                *(const float4*)(H + (size_t)r * K + k0 + cg * 4);
        }
        __syncthreads();

#pragma unroll 2
        for (int k = 0; k < 64; k += 4) {
            float4 a[4];
#pragma unroll
            for (int i = 0; i < 4; i++)
                a[i] = *(const float4*)(As + (tr * 4 + i) * AKP + k);
#pragma unroll
            for (int kk = 0; kk < 4; kk++) {
                float4 wv = *(const float4*)(Ws + (k0 + k + kk) * EMB + j0);
#pragma unroll
                for (int i = 0; i < 4; i++) {
                    float av = (kk == 0) ? a[i].x : (kk == 1) ? a[i].y
                             : (kk == 2) ? a[i].z : a[i].w;
                    acc[i][0] = fmaf(av, wv.x, acc[i][0]);
                    acc[i][1] = fmaf(av, wv.y, acc[i][1]);
                    acc[i][2] = fmaf(av, wv.z, acc[i][2]);
                    acc[i][3] = fmaf(av, wv.w, acc[i][3]);
                }
            }
        }
        __syncthreads();   // readers done before next chunk overwrites As
    }

#pragma unroll
    for (int i = 0; i < 4; i++) {
        if (r0 + i < N) {
            float s = dinv[r0 + i];
            union { __half2 h2[2]; float2 f2; } o;
            o.h2[0] = __floats2half2_rn(acc[i][0] * s, acc[i][1] * s);
            o.h2[1] = __floats2half2_rn(acc[i][2] * s, acc[i][3] * s);
            *(float2*)(G + (size_t)(r0 + i) * EMB + j0) = o.f2;
        }
    }
}

// ---------------- Aggregation: one wave per node, fp16 G rows ----------------
// R12 body (proven): 8 lanes cover one 128B fp16 G-row (dwordx4 = 8 halves
// per lane); the wave's 8 eight-lane groups each handle every 8th edge ->
// one load instruction fetches 8 rows. 4 chains -> 32 rows outstanding.
// col[] holds byte offsets; prefetched one iteration ahead. fp32 accumulate;
// epilogue combines the 8 groups with shfl_xor(8,16,32).

__device__ __forceinline__ void h8_acc(float (&a)[8], float4 raw) {
    union { float4 f4; __half2 h2[4]; } u;
    u.f4 = raw;
    float2 p0 = __half22float2(u.h2[0]);
    float2 p1 = __half22float2(u.h2[1]);
    float2 p2 = __half22float2(u.h2[2]);
    float2 p3 = __half22float2(u.h2[3]);
    a[0] += p0.x; a[1] += p0.y; a[2] += p1.x; a[3] += p1.y;
    a[4] += p2.x; a[5] += p2.y; a[6] += p3.x; a[7] += p3.y;
}

__device__ __forceinline__ void agg_node8(const __half* __restrict__ G,
                                          const int* __restrict__ coff,
                                          int s, int e, int selfoff,
                                          int grp, int f8, float (&r)[8]) {
    const char* Gb = (const char*)G + f8 * 16;   // lane's 16B slice in a row
    float a0[8] = {0.f, 0.f, 0.f, 0.f, 0.f, 0.f, 0.f, 0.f};
    float a1[8] = {0.f, 0.f, 0.f, 0.f, 0.f, 0.f, 0.f, 0.f};
    float a2[8] = {0.f, 0.f, 0.f, 0.f, 0.f, 0.f, 0.f, 0.f};
    float a3[8] = {0.f, 0.f, 0.f, 0.f, 0.f, 0.f, 0.f, 0.f};
    if (grp == 0) h8_acc(a0, *(const float4*)(Gb + selfoff));  // self loop

    int i = s;
    if (i + 32 <= e) {
        int c0 = coff[i + grp];
        int c1 = coff[i + 8 + grp];
        int c2 = coff[i + 16 + grp];
        int c3 = coff[i + 24 + grp];
        while (true) {
            float4 g0 = *(const float4*)(Gb + (size_t)(unsigned)c0);
            float4 g1 = *(const float4*)(Gb + (size_t)(unsigned)c1);
            float4 g2 = *(const float4*)(Gb + (size_t)(unsigned)c2);
            float4 g3 = *(const float4*)(Gb + (size_t)(unsigned)c3);
            i += 32;
            bool more = (i + 32 <= e);
            if (more) {                       // prefetch next iter's offsets
                c0 = coff[i + grp];
                c1 = coff[i + 8 + grp];
                c2 = coff[i + 16 + grp];
                c3 = coff[i + 24 + grp];
            }
            h8_acc(a0, g0);
            h8_acc(a1, g1);
            h8_acc(a2, g2);
            h8_acc(a3, g3);
            if (!more) break;
        }
    }
    for (; i + 8 <= e; i += 8) {
        float4 g = *(const float4*)(Gb + (size_t)(unsigned)coff[i + grp]);
        h8_acc(a1, g);
    }
    if (grp < e - i) {
        float4 g = *(const float4*)(Gb + (size_t)(unsigned)coff[i + grp]);
        h8_acc(a2, g);
    }

#pragma unroll
    for (int k = 0; k < 8; k++) {
        float v = (a0[k] + a1[k]) + (a2[k] + a3[k]);
        v += __shfl_xor(v, 8, 64);
        v += __shfl_xor(v, 16, 64);
        v += __shfl_xor(v, 32, 64);
        r[k] = v;   // all 64 lanes: full sum for features [8*f8 .. 8*f8+7]
    }
}

__global__ __launch_bounds__(256) void agg_k(
    const __half* __restrict__ G, const float* __restrict__ dinv,
    const int* __restrict__ rowptr, const int* __restrict__ coff,
    const float* __restrict__ bias, float* __restrict__ Hout, int N) {
    int gw = (blockIdx.x * 256 + threadIdx.x) >> 6;
    int lane = threadIdx.x & 63;
    if (gw >= N) return;
    gw = __builtin_amdgcn_readfirstlane(gw);    // wave-uniform -> scalar loads
    int grp = lane >> 3;
    int f8 = lane & 7;
    int s = rowptr[gw], e = rowptr[gw + 1];
    float r[8];
    agg_node8(G, coff, s, e, gw << 7, grp, f8, r);
    if (grp == 0) {
        float d = dinv[gw];
        float4 b0v = *(const float4*)(bias + f8 * 8);
        float4 b1v = *(const float4*)(bias + f8 * 8 + 4);
        float4 lo = make_float4(r[0] * d + b0v.x, r[1] * d + b0v.y,
                                r[2] * d + b0v.z, r[3] * d + b0v.w);
        float4 hi = make_float4(r[4] * d + b1v.x, r[5] * d + b1v.y,
                                r[6] * d + b1v.z, r[7] * d + b1v.w);
        float* o = Hout + (size_t)gw * EMB + f8 * 8;
        *(float4*)o = lo;
        *(float4*)(o + 4) = hi;
    }
}

// Final layer: also project y @ Wout + bout into Out.
__global__ __launch_bounds__(256) void agg_final_k(
    const __half* __restrict__ G, const float* __restrict__ dinv,
    const int* __restrict__ rowptr, const int* __restrict__ coff,
    const float* __restrict__ bias, const float* __restrict__ Wout,
    const float* __restrict__ bout, float* __restrict__ Y,
    float* __restrict__ Out, int N) {
    int gw = (blockIdx.x * 256 + threadIdx.x) >> 6;
    int lane = threadIdx.x & 63;
    if (gw >= N) return;
    gw = __builtin_amdgcn_readfirstlane(gw);
    int grp = lane >> 3;
    int f8 = lane & 7;
    int s = rowptr[gw], e = rowptr[gw + 1];
    float r[8];
    agg_node8(G, coff, s, e, gw << 7, grp, f8, r);
    float d = dinv[gw];
    float4 b0v = *(const float4*)(bias + f8 * 8);
    float4 b1v = *(const float4*)(bias + f8 * 8 + 4);
    float v0 = r[0] * d + b0v.x, v1 = r[1] * d + b0v.y;
    float v2 = r[2] * d + b0v.z, v3 = r[3] * d + b0v.w;
    float v4 = r[4] * d + b1v.x, v5 = r[5] * d + b1v.y;
    float v6 = r[6] * d + b1v.z, v7 = r[7] * d + b1v.w;
    if (grp == 0) {
        float* o = Y + (size_t)gw * EMB + f8 * 8;
        *(float4*)o = make_float4(v0, v1, v2, v3);
        *(float4*)(o + 4) = make_float4(v4, v5, v6, v7);
    }
    // output projection: each lane holds 8 features; lanes 0..7 cover all 64.
    float4 w0v = *(const float4*)(Wout + f8 * 8);
    float4 w1v = *(const float4*)(Wout + f8 * 8 + 4);
    float p = v0 * w0v.x + v1 * w0v.y + v2 * w0v.z + v3 * w0v.w +
              v4 * w1v.x + v5 * w1v.y + v6 * w1v.z + v7 * w1v.w;
    p += __shfl_xor(p, 1, 8);
    p += __shfl_xor(p, 2, 8);
    p += __shfl_xor(p, 4, 8);
    if (lane == 0) Out[gw] = p + bout[0];
}

// ---------------- launch ----------------

extern "C" void kernel_launch(void* const* d_in, const int* in_sizes, int n_in,
                              void* d_out, int out_size, void* d_ws, size_t ws_size,
                              hipStream_t stream) {
    const float* x    = (const float*)d_in[0];
    const int*   ei   = (const int*)d_in[1];
    const float* W0   = (const float*)d_in[3];
    const float* b0   = (const float*)d_in[4];
    const float* W1   = (const float*)d_in[5];
    const float* b1   = (const float*)d_in[6];
    const float* W2   = (const float*)d_in[7];
    const float* b2   = (const float*)d_in[8];
    const float* W3   = (const float*)d_in[9];
    const float* b3   = (const float*)d_in[10];
    const float* Wout = (const float*)d_in[11];
    const float* bout = (const float*)d_in[12];

    const int N = in_sizes[0] / FEAT;      // 100000
    const int E = in_sizes[1] / 2;         // 3200000
    const int* srcp = ei;                  // edge_index[0]
    const int* dstp = ei + E;              // edge_index[1]
    const int nbin = (N + BINSIZE - 1) / BINSIZE;   // 391

    // workspace layout (regions padded to 64 elems for float4 alignment)
    const int NP = ((N + 64) + 63) / 64 * 64;   // holds N+1
    float* dinv  = (float*)d_ws;
    int* rowptr  = (int*)(dinv + NP);
    int* bincnt  = rowptr + NP;
    int* binptr  = bincnt + 1024;
    int* bincur  = binptr + 1024;
    int* col     = bincur + 1024;
    float* bufA  = (float*)(col + ((E + 63) / 64) * 64);
    int* ebuf    = (int*)bufA;            // aliased: ebuf dead before first gemm
    __half* Gbuf = (__half*)bufA;         // fp16 G (12.8MB) also aliases here

    float* Out = (float*)d_out;
    float* Y   = Out + N;                 // reuse y-region of d_out as ping-pong buffer

    const int gemm_blocks = (N + 63) / 64;
    const int agg_blocks  = (N + 3) / 4;
    const int nchunk = (E + CHUNK - 1) / CHUNK;

    // --- CSR build ---
    hipMemsetAsync(bincnt, 0, 1024 * sizeof(int), stream);
    bin_count_k<<<nchunk, 256, 0, stream>>>(dstp, bincnt, E);
    binscan_k<<<1, 512, 0, stream>>>(bincnt, binptr, bincur, nbin, E);
    bin_edges_k<<<nchunk, 256, 0, stream>>>(srcp, dstp, bincur, ebuf, E);
    build_csr_k<<<nbin, 256, 0, stream>>>(ebuf, binptr, rowptr, dinv, col, N, E, nbin);

    // --- layer 0 (K=128) ---
    gemm_scale_k<FEAT><<<gemm_blocks, 256, 0, stream>>>(x, W0, dinv, Gbuf, N);
    agg_k<<<agg_blocks, 256, 0, stream>>>(Gbuf, dinv, rowptr, col, b0, Y, N);
    // --- layer 1 ---
    gemm_scale_k<EMB><<<gemm_blocks, 256, 0, stream>>>(Y, W1, dinv, Gbuf, N);
    agg_k<<<agg_blocks, 256, 0, stream>>>(Gbuf, dinv, rowptr, col, b1, Y, N);
    // --- layer 2 ---
    gemm_scale_k<EMB><<<gemm_blocks, 256, 0, stream>>>(Y, W2, dinv, Gbuf, N);
    agg_k<<<agg_blocks, 256, 0, stream>>>(Gbuf, dinv, rowptr, col, b2, Y, N);
    // --- layer 3 + output projection ---
    gemm_scale_k<EMB><<<gemm_blocks, 256, 0, stream>>>(Y, W3, dinv, Gbuf, N);
    agg_final_k<<<agg_blocks, 256, 0, stream>>>(Gbuf, dinv, rowptr, col, b3, Wout, bout,
                                                Y, Out, N);
}